// Round 15
// baseline (9783.563 us; speedup 1.0000x reference)
//
#include <hip/hip_runtime.h>

#define IN_F 4096
#define OUT_F 11008

typedef __attribute__((ext_vector_type(8))) short bf16x8;   // 8 bf16 (4 VGPR) MFMA operand
typedef __attribute__((ext_vector_type(4))) float f32x4;
typedef __attribute__((ext_vector_type(4))) unsigned short us4;
typedef __attribute__((ext_vector_type(8))) unsigned short us8;

__device__ __forceinline__ unsigned short f2bf(float f) {
  unsigned int u = __float_as_uint(f);
  u += 0x7FFFu + ((u >> 16) & 1u);   // RNE
  return (unsigned short)(u >> 16);
}

// ---------------- prepass 1: X fp32 -> bf16 ----------------
__global__ __launch_bounds__(256) void cvt_x(const float* __restrict__ X,
                                             unsigned short* __restrict__ Xb, int n8) {
  for (int i = blockIdx.x * blockDim.x + threadIdx.x; i < n8;
       i += gridDim.x * blockDim.x) {
    const float4 a = reinterpret_cast<const float4*>(X)[2 * i];
    const float4 b = reinterpret_cast<const float4*>(X)[2 * i + 1];
    us8 h;
    h[0] = f2bf(a.x); h[1] = f2bf(a.y); h[2] = f2bf(a.z); h[3] = f2bf(a.w);
    h[4] = f2bf(b.x); h[5] = f2bf(b.y); h[6] = f2bf(b.z); h[7] = f2bf(b.w);
    reinterpret_cast<us8*>(Xb)[i] = h;
  }
}

// ---------------- prepass 2: W nf4 packed -> bf16 (dequant once) ----------------
__global__ __launch_bounds__(256) void dequant_w(const int* __restrict__ Wp,
                                                 const float* __restrict__ Amax,
                                                 unsigned short* __restrict__ Wb, int n4) {
  __shared__ float lutS[16];
  if (threadIdx.x < 16) {
    const float lut[16] = {-1.0f, -0.6961928009986877f, -0.5250730514526367f,
        -0.39491719007492065f, -0.28444138169288635f, -0.18477343022823334f,
        -0.08820830285549164f, 0.0f, 0.07107656449079514f, 0.14263366162776947f,
        0.22430233657360077f, 0.3203405737876892f, 0.4407068192958832f,
        0.5905631184577942f, 0.796090841293335f, 1.0f};
    lutS[threadIdx.x] = lut[threadIdx.x];
  }
  __syncthreads();
  for (int i = blockIdx.x * blockDim.x + threadIdx.x; i < n4;
       i += gridDim.x * blockDim.x) {
    const int j = i * 4;
    const int row = j >> 11;
    const int coli = j & 2047;
    const float am = Amax[row * (IN_F / 64) + (coli >> 5)];
    const int4 pk = reinterpret_cast<const int4*>(Wp)[i];
    us8 h; int c;
    c = pk.x & 255; h[0] = f2bf(lutS[c & 15] * am); h[1] = f2bf(lutS[c >> 4] * am);
    c = pk.y & 255; h[2] = f2bf(lutS[c & 15] * am); h[3] = f2bf(lutS[c >> 4] * am);
    c = pk.z & 255; h[4] = f2bf(lutS[c & 15] * am); h[5] = f2bf(lutS[c >> 4] * am);
    c = pk.w & 255; h[6] = f2bf(lutS[c & 15] * am); h[7] = f2bf(lutS[c >> 4] * am);
    reinterpret_cast<us8*>(Wb)[i] = h;
  }
}

// ------- main GEMM: 256x256 tile, 16 waves, BK=32, ring-2 LDS (64 KiB), 2 blocks/CU -------
#define MF(a, b, c) __builtin_amdgcn_mfma_f32_16x16x32_bf16(a, b, c, 0, 0, 0)
#define GLDS(src, dst) __builtin_amdgcn_global_load_lds( \
    (const __attribute__((address_space(1))) void*)(src), \
    (__attribute__((address_space(3))) void*)(dst), 16, 0, 0)
#define BAR __builtin_amdgcn_s_barrier()
#define VM0 asm volatile("s_waitcnt vmcnt(0)")
#define P1 __builtin_amdgcn_s_setprio(1)
#define P0 __builtin_amdgcn_s_setprio(0)

__global__ __launch_bounds__(1024, 8) void gemm256w16(
    const unsigned short* __restrict__ A,   // (M, K) bf16
    const unsigned short* __restrict__ B,   // (N, K) bf16
    const float* __restrict__ Bias, float* __restrict__ Out, int M) {
  extern __shared__ unsigned short sm[];    // 64 KiB: 2 slots x {A 16KB, B 16KB}
  char* const smc = (char*)sm;

  const int tid = threadIdx.x;
  const int l = tid & 63;
  const int wid = tid >> 6;                 // 0..15

  const int Nb = OUT_F / 256;               // 43

  // Supertile order: 16 m-rows x all Nb per supertile (A window 32MB L3-resident),
  // XCD-chunked inside (bps = 16*Nb, %8==0; launcher guards M%4096==0).
  const int bps = 16 * Nb;                  // 688
  const int pxc = bps >> 3;                 // 86
  const int i6 = (int)blockIdx.x % bps;
  const int sup = (int)blockIdx.x / bps;
  const int kk = (i6 & 7) * pxc + (i6 >> 3);
  const int m0 = (sup * 16 + (kk & 15)) * 256;
  const int n0 = (kk >> 4) * 256;

  const int wm = (wid >> 2) * 64;           // 4x4 wave grid, per-wave 64x64
  const int wn = (wid & 3) * 64;

  // read-side lane constant (r12/r14-proven, 0 conflicts): row rl=l&15, k-slice s=l>>4,
  // logical (r,c) stored at 16B-chunk c ^ ((r>>1)&3); 64B rows.
  const int lv = (l & 15) * 64 + (((l >> 4) ^ ((l >> 1) & 3)) * 16);   // bytes
  const int aLane = (wid >> 2) * 4096 + lv;             // + i*1024 per A frag
  const int bLane = 16384 + (wid & 3) * 4096 + lv;      // + j*1024 per B frag

  // stage-side lane constants (inverse-swizzled global source, linear LDS dest):
  // thread tid -> unit row tid>>2 (of 256), holds global k-chunk (tid&3)^(((tid>>2)>>1)&3)
  const int rq = tid >> 2;
  const int cs = (tid & 3) ^ ((tid >> 3) & 3);
  const unsigned short* gAs = A + (size_t)(m0 + rq) * IN_F + cs * 8;
  const unsigned short* gBs = B + (size_t)(n0 + rq) * IN_F + cs * 8;

  // unit = 16 KiB (256 rows x 32 k) = ONE glds for the 1024-thread block.
  // slot sl (32 KiB = 16384 elems): A @ +0, B @ +8192 elems.
#define SA(t, sl) GLDS(gAs + (size_t)(t) * 32, sm + (sl) * 16384 + wid * 512)
#define SB(t, sl) GLDS(gBs + (size_t)(t) * 32, sm + (sl) * 16384 + 8192 + wid * 512)

  f32x4 acc[4][4];
#pragma unroll
  for (int i = 0; i < 4; ++i)
#pragma unroll
    for (int j = 0; j < 4; ++j) acc[i][j] = {0.f, 0.f, 0.f, 0.f};

  // KT(T, STG): VM0 | BAR | 8 reads(slot T&1) | stage T+1 -> slot (T+1)&1 | 16 MFMA.
  // Lookahead-1 ring-2: entering T, outstanding = T's pair (issued during T-1, ~2500
  //   cyc ago >> HBM latency) -> VM0 rarely blocks; the co-resident 2nd block covers it.
  // Data-ready: every wave's VM0 precedes BAR@T; reads follow BAR@T.
  // WAR: stage(T+1) -> slot (T+1)&1 = slot of T-1, whose reads each wave consumed
  //   (register deps into T-1's MFMAs) before reaching BAR@T; stages issue after BAR@T.
#define KT(T, STG) do { \
    VM0; \
    BAR; \
    const char* Sb = smc + ((T) & 1) * 32768; \
    bf16x8 a0, a1, a2, a3, b0, b1, b2, b3; \
    a0 = *(const bf16x8*)(Sb + aLane);        a1 = *(const bf16x8*)(Sb + aLane + 1024); \
    a2 = *(const bf16x8*)(Sb + aLane + 2048); a3 = *(const bf16x8*)(Sb + aLane + 3072); \
    b0 = *(const bf16x8*)(Sb + bLane);        b1 = *(const bf16x8*)(Sb + bLane + 1024); \
    b2 = *(const bf16x8*)(Sb + bLane + 2048); b3 = *(const bf16x8*)(Sb + bLane + 3072); \
    if (STG) { SA((T) + 1, ((T) + 1) & 1); SB((T) + 1, ((T) + 1) & 1); } \
    P1; \
    acc[0][0]=MF(a0,b0,acc[0][0]); acc[0][1]=MF(a0,b1,acc[0][1]); \
    acc[0][2]=MF(a0,b2,acc[0][2]); acc[0][3]=MF(a0,b3,acc[0][3]); \
    acc[1][0]=MF(a1,b0,acc[1][0]); acc[1][1]=MF(a1,b1,acc[1][1]); \
    acc[1][2]=MF(a1,b2,acc[1][2]); acc[1][3]=MF(a1,b3,acc[1][3]); \
    acc[2][0]=MF(a2,b0,acc[2][0]); acc[2][1]=MF(a2,b1,acc[2][1]); \
    acc[2][2]=MF(a2,b2,acc[2][2]); acc[2][3]=MF(a2,b3,acc[2][3]); \
    acc[3][0]=MF(a3,b0,acc[3][0]); acc[3][1]=MF(a3,b1,acc[3][1]); \
    acc[3][2]=MF(a3,b2,acc[3][2]); acc[3][3]=MF(a3,b3,acc[3][3]); \
    P0; \
  } while (0)

  // prologue: stage tile 0 (slot 0); KT(0)'s VM0+BAR is the sync.
  SA(0, 0); SB(0, 0);

  for (int T = 0; T < 127; ++T) { KT(T, 1); }
  KT(127, 0);

  // epilogue: C = acc + bias   (C/D map: col = l&15, row = (l>>4)*4 + reg)
  const int crow0 = m0 + wm + ((l >> 4) << 2);
  const int ccol0 = n0 + wn + (l & 15);
#pragma unroll
  for (int j = 0; j < 4; ++j) {
    const float bv = Bias[ccol0 + j * 16];
#pragma unroll
    for (int i = 0; i < 4; ++i)
#pragma unroll
      for (int rg = 0; rg < 4; ++rg)
        Out[(size_t)(crow0 + i * 16 + rg) * OUT_F + ccol0 + j * 16] = acc[i][j][rg] + bv;
  }
}

// ---------------- fallback: fused kernel (if ws too small / shape off) ----------------
__global__ __launch_bounds__(256, 2) void nf4_gemm_fused(
    const float* __restrict__ X, const int* __restrict__ Wp,
    const float* __restrict__ Amax, const float* __restrict__ Bias,
    float* __restrict__ Out, int M) {
  __shared__ unsigned short As[128 * 64];
  __shared__ unsigned short Bs[128 * 64];
  __shared__ float lutS[16];

  const int t = threadIdx.x;
  const int l = t & 63;
  const int wid = t >> 6;

  if (t < 16) {
    const float lut[16] = {-1.0f, -0.6961928009986877f, -0.5250730514526367f,
        -0.39491719007492065f, -0.28444138169288635f, -0.18477343022823334f,
        -0.08820830285549164f, 0.0f, 0.07107656449079514f, 0.14263366162776947f,
        0.22430233657360077f, 0.3203405737876892f, 0.4407068192958832f,
        0.5905631184577942f, 0.796090841293335f, 1.0f};
    lutS[t] = lut[t];
  }

  const int ntile = OUT_F / 128;
  const int m0 = (blockIdx.x / ntile) * 128;
  const int n0 = (blockIdx.x % ntile) * 128;

  const int ar = t >> 4;
  const int ac4 = t & 15;
  const int br = t >> 3;
  const int bg = t & 7;
  const int wm = (wid >> 1) * 64;
  const int wn = (wid & 1) * 64;

  f32x4 acc[4][4];
#pragma unroll
  for (int i = 0; i < 4; ++i)
#pragma unroll
    for (int j = 0; j < 4; ++j) acc[i][j] = {0.f, 0.f, 0.f, 0.f};

  __syncthreads();

  for (int k0 = 0; k0 < IN_F; k0 += 64) {
#pragma unroll
    for (int p = 0; p < 8; ++p) {
      const int r = p * 16 + ar;
      const float4 v = *reinterpret_cast<const float4*>(
          X + (size_t)(m0 + r) * IN_F + k0 + ac4 * 4);
      us4 h;
      h[0] = f2bf(v.x); h[1] = f2bf(v.y); h[2] = f2bf(v.z); h[3] = f2bf(v.w);
      const int byte = r * 128 + ((ac4 * 8) ^ ((r & 7) << 4));
      *reinterpret_cast<us4*>(reinterpret_cast<char*>(As) + byte) = h;
    }
#pragma unroll
    for (int p = 0; p < 4; ++p) {
      const int r = p * 32 + br;
      const float amv = Amax[(size_t)(n0 + r) * (IN_F / 64) + (k0 >> 6)];
      const int4 pk = *reinterpret_cast<const int4*>(
          Wp + (size_t)(n0 + r) * (IN_F / 2) + (k0 >> 1) + bg * 4);
      us8 h;
      {
        int c;
        c = pk.x & 255; h[0] = f2bf(lutS[c & 15] * amv); h[1] = f2bf(lutS[c >> 4] * amv);
        c = pk.y & 255; h[2] = f2bf(lutS[c & 15] * amv); h[3] = f2bf(lutS[c >> 4] * amv);
        c = pk.z & 255; h[4] = f2bf(lutS[c & 15] * amv); h[5] = f2bf(lutS[c >> 4] * amv);
        c = pk.w & 255; h[6] = f2bf(lutS[c & 15] * amv); h[7] = f2bf(lutS[c >> 4] * amv);
      }
      const int byte = r * 128 + ((bg * 16) ^ ((r & 7) << 4));
      *reinterpret_cast<us8*>(reinterpret_cast<char*>(Bs) + byte) = h;
    }
    __syncthreads();

#pragma unroll
    for (int kkk = 0; kkk < 64; kkk += 32) {
      bf16x8 af[4], bfv[4];
      const int kb = (kkk + ((l >> 4) << 3)) * 2;
#pragma unroll
      for (int i = 0; i < 4; ++i) {
        const int row = wm + i * 16 + (l & 15);
        af[i] = *reinterpret_cast<const bf16x8*>(
            reinterpret_cast<const char*>(As) + row * 128 + (kb ^ ((row & 7) << 4)));
      }
#pragma unroll
      for (int j = 0; j < 4; ++j) {
        const int row = wn + j * 16 + (l & 15);
        bfv[j] = *reinterpret_cast<const bf16x8*>(
            reinterpret_cast<const char*>(Bs) + row * 128 + (kb ^ ((row & 7) << 4)));
      }
#pragma unroll
      for (int i = 0; i < 4; ++i)
#pragma unroll
        for (int j = 0; j < 4; ++j)
          acc[i][j] = __builtin_amdgcn_mfma_f32_16x16x32_bf16(af[i], bfv[j], acc[i][j], 0, 0, 0);
    }
    __syncthreads();
  }

  const int crow0 = m0 + wm + ((l >> 4) << 2);
  const int ccol0 = n0 + wn + (l & 15);
#pragma unroll
  for (int j = 0; j < 4; ++j) {
    const float bv = Bias[ccol0 + j * 16];
#pragma unroll
    for (int i = 0; i < 4; ++i)
#pragma unroll
      for (int rg = 0; rg < 4; ++rg)
        Out[(size_t)(crow0 + i * 16 + rg) * OUT_F + ccol0 + j * 16] = acc[i][j][rg] + bv;
  }
}

extern "C" void kernel_launch(void* const* d_in, const int* in_sizes, int n_in,
                              void* d_out, int out_size, void* d_ws, size_t ws_size,
                              hipStream_t stream) {
  const float* X = (const float*)d_in[0];
  const int* Wp = (const int*)d_in[1];
  const float* Amax = (const float*)d_in[2];
  const float* Bias = (const float*)d_in[3];
  float* Out = (float*)d_out;

  const int M = in_sizes[0] / IN_F;                       // 8192
  const size_t needX = (size_t)M * IN_F * 2;
  const size_t needW = (size_t)OUT_F * IN_F * 2;
  const int grid256 = (M / 256) * (OUT_F / 256);          // 32*43 = 1376

  if (ws_size >= needX + needW && (M % 4096) == 0) {      // Mb%16==0 for supertile map
    unsigned short* Xb = (unsigned short*)d_ws;
    unsigned short* Wb = Xb + (size_t)M * IN_F;
    (void)hipFuncSetAttribute(reinterpret_cast<const void*>(gemm256w16),
                              hipFuncAttributeMaxDynamicSharedMemorySize, 65536);
    cvt_x<<<2048, 256, 0, stream>>>(X, Xb, M * (IN_F / 8));
    dequant_w<<<2048, 256, 0, stream>>>(Wp, Amax, Wb, OUT_F * (IN_F / 8));
    gemm256w16<<<grid256, 1024, 65536, stream>>>(Xb, Wb, Bias, Out, M);
  } else {
    const int grid = (M / 128) * (OUT_F / 128);
    nf4_gemm_fused<<<grid, 256, 0, stream>>>(X, Wp, Amax, Bias, Out, M);
  }
}

// Round 16
// 746.367 us; speedup vs baseline: 13.1083x; 13.1083x over previous
//
#include <hip/hip_runtime.h>

#define IN_F 4096
#define OUT_F 11008

typedef __attribute__((ext_vector_type(8))) short bf16x8;   // 8 bf16 (4 VGPR) MFMA operand
typedef __attribute__((ext_vector_type(4))) float f32x4;
typedef __attribute__((ext_vector_type(4))) unsigned short us4;
typedef __attribute__((ext_vector_type(8))) unsigned short us8;

__device__ __forceinline__ unsigned short f2bf(float f) {
  unsigned int u = __float_as_uint(f);
  u += 0x7FFFu + ((u >> 16) & 1u);   // RNE
  return (unsigned short)(u >> 16);
}

// ---------------- merged prepass: X fp32->bf16  +  W nf4->bf16 (dequant once) ----------------
// blocks [0, xblk): cvt X; blocks [xblk, xblk+wblk): dequant W. Both HBM-bound.
__global__ __launch_bounds__(256) void prepass(const float* __restrict__ X,
                                               unsigned short* __restrict__ Xb, int n8,
                                               const int* __restrict__ Wp,
                                               const float* __restrict__ Amax,
                                               unsigned short* __restrict__ Wb, int n4,
                                               int xblk) {
  __shared__ float lutS[16];
  if (threadIdx.x < 16) {
    const float lut[16] = {-1.0f, -0.6961928009986877f, -0.5250730514526367f,
        -0.39491719007492065f, -0.28444138169288635f, -0.18477343022823334f,
        -0.08820830285549164f, 0.0f, 0.07107656449079514f, 0.14263366162776947f,
        0.22430233657360077f, 0.3203405737876892f, 0.4407068192958832f,
        0.5905631184577942f, 0.796090841293335f, 1.0f};
    lutS[threadIdx.x] = lut[threadIdx.x];
  }
  __syncthreads();
  if ((int)blockIdx.x < xblk) {
    for (int i = blockIdx.x * blockDim.x + threadIdx.x; i < n8;
         i += xblk * blockDim.x) {
      const float4 a = reinterpret_cast<const float4*>(X)[2 * i];
      const float4 b = reinterpret_cast<const float4*>(X)[2 * i + 1];
      us8 h;
      h[0] = f2bf(a.x); h[1] = f2bf(a.y); h[2] = f2bf(a.z); h[3] = f2bf(a.w);
      h[4] = f2bf(b.x); h[5] = f2bf(b.y); h[6] = f2bf(b.z); h[7] = f2bf(b.w);
      reinterpret_cast<us8*>(Xb)[i] = h;
    }
  } else {
    const int wgrid = gridDim.x - xblk;
    for (int i = (blockIdx.x - xblk) * blockDim.x + threadIdx.x; i < n4;
         i += wgrid * blockDim.x) {
      const int j = i * 4;
      const int row = j >> 11;
      const int coli = j & 2047;
      const float am = Amax[row * (IN_F / 64) + (coli >> 5)];
      const int4 pk = reinterpret_cast<const int4*>(Wp)[i];
      us8 h; int c;
      c = pk.x & 255; h[0] = f2bf(lutS[c & 15] * am); h[1] = f2bf(lutS[c >> 4] * am);
      c = pk.y & 255; h[2] = f2bf(lutS[c & 15] * am); h[3] = f2bf(lutS[c >> 4] * am);
      c = pk.z & 255; h[4] = f2bf(lutS[c & 15] * am); h[5] = f2bf(lutS[c >> 4] * am);
      c = pk.w & 255; h[6] = f2bf(lutS[c & 15] * am); h[7] = f2bf(lutS[c >> 4] * am);
      reinterpret_cast<us8*>(Wb)[i] = h;
    }
  }
}

// ------- main GEMM (r14-proven): 256x256 tile, 16 waves (4/SIMD), BK=32, ring-3 96 KiB -------
#define MF(a, b, c) __builtin_amdgcn_mfma_f32_16x16x32_bf16(a, b, c, 0, 0, 0)
#define GLDS(src, dst) __builtin_amdgcn_global_load_lds( \
    (const __attribute__((address_space(1))) void*)(src), \
    (__attribute__((address_space(3))) void*)(dst), 16, 0, 0)
#define BAR __builtin_amdgcn_s_barrier()
#define VM2 asm volatile("s_waitcnt vmcnt(2)")
#define VM0 asm volatile("s_waitcnt vmcnt(0)")
#define P1 __builtin_amdgcn_s_setprio(1)
#define P0 __builtin_amdgcn_s_setprio(0)

__global__ __launch_bounds__(1024, 4) void gemm256w16(
    const unsigned short* __restrict__ A,   // (M, K) bf16
    const unsigned short* __restrict__ B,   // (N, K) bf16
    const float* __restrict__ Bias, float* __restrict__ Out, int M) {
  extern __shared__ unsigned short sm[];    // 96 KiB: 3 slots x {A 16KB, B 16KB}
  char* const smc = (char*)sm;

  const int tid = threadIdx.x;
  const int l = tid & 63;
  const int wid = tid >> 6;                 // 0..15

  const int Nb = OUT_F / 256;               // 43

  // Supertile order: 16 m-rows x all Nb per supertile (A window 32MB L3-resident),
  // XCD-chunked inside (bps = 16*Nb, %8==0; launcher guards M%4096==0).
  const int bps = 16 * Nb;                  // 688
  const int pxc = bps >> 3;                 // 86
  const int i6 = (int)blockIdx.x % bps;
  const int sup = (int)blockIdx.x / bps;
  const int kk = (i6 & 7) * pxc + (i6 >> 3);
  const int m0 = (sup * 16 + (kk & 15)) * 256;
  const int n0 = (kk >> 4) * 256;

  const int wm = (wid >> 2) * 64;           // 4x4 wave grid, per-wave 64x64
  const int wn = (wid & 3) * 64;

  // read-side lane constant (r12/r14-proven, 0 conflicts): row rl=l&15, k-slice s=l>>4,
  // logical (r,c) stored at 16B-chunk c ^ ((r>>1)&3); 64B rows.
  const int lv = (l & 15) * 64 + (((l >> 4) ^ ((l >> 1) & 3)) * 16);   // bytes
  const int aLane = (wid >> 2) * 4096 + lv;             // + i*1024 per A frag
  const int bLane = 16384 + (wid & 3) * 4096 + lv;      // + j*1024 per B frag

  // stage-side lane constants (inverse-swizzled global source, linear LDS dest):
  // thread tid -> unit row tid>>2 (of 256), holds global k-chunk (tid&3)^(((tid>>2)>>1)&3)
  const int rq = tid >> 2;
  const int cs = (tid & 3) ^ ((tid >> 3) & 3);
  const unsigned short* gAs = A + (size_t)(m0 + rq) * IN_F + cs * 8;
  const unsigned short* gBs = B + (size_t)(n0 + rq) * IN_F + cs * 8;

  // unit = 16 KiB (256 rows x 32 k) = ONE glds for the 1024-thread block.
  // slot sl (32 KiB = 16384 elems): A @ +0, B @ +8192 elems.
#define SA(t, sl) GLDS(gAs + (size_t)(t) * 32, sm + (sl) * 16384 + wid * 512)
#define SB(t, sl) GLDS(gBs + (size_t)(t) * 32, sm + (sl) * 16384 + 8192 + wid * 512)

  f32x4 acc[4][4];
#pragma unroll
  for (int i = 0; i < 4; ++i)
#pragma unroll
    for (int j = 0; j < 4; ++j) acc[i][j] = {0.f, 0.f, 0.f, 0.f};

  // KT(T, SL, STG, VMW): VMW | BAR | 8 reads(slot SL) | SA(T+2) | 8 MFMA | SB(T+2) | 8 MFMA.
  // Queue induction: entering T, in flight = {T's 2 (issued T-2), T+1's 2 (issued T-1)};
  //   VM2 retires exactly T's pair; body issues T+2's pair. Tail: VM2@126, VM0@127.
  // Data-ready: every wave's VMW precedes BAR@T; reads follow BAR@T.
  // WAR: slot (SL+2)%3 = slot of tile T-1, whose reads all waves lgkm-consumed (register
  //   deps into tile T-1's MFMAs) before reaching BAR@T; stages issue after BAR@T.
#define KT(T, SL, STG, VMW) do { \
    VMW; \
    BAR; \
    const char* Sb = smc + (SL) * 32768; \
    bf16x8 a0, a1, a2, a3, b0, b1, b2, b3; \
    a0 = *(const bf16x8*)(Sb + aLane);        a1 = *(const bf16x8*)(Sb + aLane + 1024); \
    a2 = *(const bf16x8*)(Sb + aLane + 2048); a3 = *(const bf16x8*)(Sb + aLane + 3072); \
    b0 = *(const bf16x8*)(Sb + bLane);        b1 = *(const bf16x8*)(Sb + bLane + 1024); \
    b2 = *(const bf16x8*)(Sb + bLane + 2048); b3 = *(const bf16x8*)(Sb + bLane + 3072); \
    if (STG) SA((T) + 2, ((SL) + 2) % 3); \
    P1; \
    acc[0][0]=MF(a0,b0,acc[0][0]); acc[0][1]=MF(a0,b1,acc[0][1]); \
    acc[0][2]=MF(a0,b2,acc[0][2]); acc[0][3]=MF(a0,b3,acc[0][3]); \
    acc[1][0]=MF(a1,b0,acc[1][0]); acc[1][1]=MF(a1,b1,acc[1][1]); \
    acc[1][2]=MF(a1,b2,acc[1][2]); acc[1][3]=MF(a1,b3,acc[1][3]); \
    P0; \
    if (STG) SB((T) + 2, ((SL) + 2) % 3); \
    P1; \
    acc[2][0]=MF(a2,b0,acc[2][0]); acc[2][1]=MF(a2,b1,acc[2][1]); \
    acc[2][2]=MF(a2,b2,acc[2][2]); acc[2][3]=MF(a2,b3,acc[2][3]); \
    acc[3][0]=MF(a3,b0,acc[3][0]); acc[3][1]=MF(a3,b1,acc[3][1]); \
    acc[3][2]=MF(a3,b2,acc[3][2]); acc[3][3]=MF(a3,b3,acc[3][3]); \
    P0; \
  } while (0)

  // prologue: stage tiles 0 (slot 0) and 1 (slot 1); KT(0)'s VM2+BAR is the sync.
  SA(0, 0); SB(0, 0); SA(1, 1); SB(1, 1);

  // 128 K-tiles of 32; slots cycle T%3; stages stop at T=125.
  for (int T = 0; T < 126; T += 3) {
    KT(T, 0, (T < 124), VM2);
    KT(T + 1, 1, (T + 1 < 126), VM2);
    KT(T + 2, 2, (T + 2 < 126), VM2);
  }
  KT(126, 0, 0, VM2);
  KT(127, 1, 0, VM0);

  // epilogue: C = acc + bias   (C/D map: col = l&15, row = (l>>4)*4 + reg)
  const int crow0 = m0 + wm + ((l >> 4) << 2);
  const int ccol0 = n0 + wn + (l & 15);
#pragma unroll
  for (int j = 0; j < 4; ++j) {
    const float bv = Bias[ccol0 + j * 16];
#pragma unroll
    for (int i = 0; i < 4; ++i)
#pragma unroll
      for (int rg = 0; rg < 4; ++rg)
        Out[(size_t)(crow0 + i * 16 + rg) * OUT_F + ccol0 + j * 16] = acc[i][j][rg] + bv;
  }
}

// ---------------- fallback: fused kernel (if ws too small / shape off) ----------------
__global__ __launch_bounds__(256, 2) void nf4_gemm_fused(
    const float* __restrict__ X, const int* __restrict__ Wp,
    const float* __restrict__ Amax, const float* __restrict__ Bias,
    float* __restrict__ Out, int M) {
  __shared__ unsigned short As[128 * 64];
  __shared__ unsigned short Bs[128 * 64];
  __shared__ float lutS[16];

  const int t = threadIdx.x;
  const int l = t & 63;
  const int wid = t >> 6;

  if (t < 16) {
    const float lut[16] = {-1.0f, -0.6961928009986877f, -0.5250730514526367f,
        -0.39491719007492065f, -0.28444138169288635f, -0.18477343022823334f,
        -0.08820830285549164f, 0.0f, 0.07107656449079514f, 0.14263366162776947f,
        0.22430233657360077f, 0.3203405737876892f, 0.4407068192958832f,
        0.5905631184577942f, 0.796090841293335f, 1.0f};
    lutS[t] = lut[t];
  }

  const int ntile = OUT_F / 128;
  const int m0 = (blockIdx.x / ntile) * 128;
  const int n0 = (blockIdx.x % ntile) * 128;

  const int ar = t >> 4;
  const int ac4 = t & 15;
  const int br = t >> 3;
  const int bg = t & 7;
  const int wm = (wid >> 1) * 64;
  const int wn = (wid & 1) * 64;

  f32x4 acc[4][4];
#pragma unroll
  for (int i = 0; i < 4; ++i)
#pragma unroll
    for (int j = 0; j < 4; ++j) acc[i][j] = {0.f, 0.f, 0.f, 0.f};

  __syncthreads();

  for (int k0 = 0; k0 < IN_F; k0 += 64) {
#pragma unroll
    for (int p = 0; p < 8; ++p) {
      const int r = p * 16 + ar;
      const float4 v = *reinterpret_cast<const float4*>(
          X + (size_t)(m0 + r) * IN_F + k0 + ac4 * 4);
      us4 h;
      h[0] = f2bf(v.x); h[1] = f2bf(v.y); h[2] = f2bf(v.z); h[3] = f2bf(v.w);
      const int byte = r * 128 + ((ac4 * 8) ^ ((r & 7) << 4));
      *reinterpret_cast<us4*>(reinterpret_cast<char*>(As) + byte) = h;
    }
#pragma unroll
    for (int p = 0; p < 4; ++p) {
      const int r = p * 32 + br;
      const float amv = Amax[(size_t)(n0 + r) * (IN_F / 64) + (k0 >> 6)];
      const int4 pk = *reinterpret_cast<const int4*>(
          Wp + (size_t)(n0 + r) * (IN_F / 2) + (k0 >> 1) + bg * 4);
      us8 h;
      {
        int c;
        c = pk.x & 255; h[0] = f2bf(lutS[c & 15] * amv); h[1] = f2bf(lutS[c >> 4] * amv);
        c = pk.y & 255; h[2] = f2bf(lutS[c & 15] * amv); h[3] = f2bf(lutS[c >> 4] * amv);
        c = pk.z & 255; h[4] = f2bf(lutS[c & 15] * amv); h[5] = f2bf(lutS[c >> 4] * amv);
        c = pk.w & 255; h[6] = f2bf(lutS[c & 15] * amv); h[7] = f2bf(lutS[c >> 4] * amv);
      }
      const int byte = r * 128 + ((bg * 16) ^ ((r & 7) << 4));
      *reinterpret_cast<us8*>(reinterpret_cast<char*>(Bs) + byte) = h;
    }
    __syncthreads();

#pragma unroll
    for (int kkk = 0; kkk < 64; kkk += 32) {
      bf16x8 af[4], bfv[4];
      const int kb = (kkk + ((l >> 4) << 3)) * 2;
#pragma unroll
      for (int i = 0; i < 4; ++i) {
        const int row = wm + i * 16 + (l & 15);
        af[i] = *reinterpret_cast<const bf16x8*>(
            reinterpret_cast<const char*>(As) + row * 128 + (kb ^ ((row & 7) << 4)));
      }
#pragma unroll
      for (int j = 0; j < 4; ++j) {
        const int row = wn + j * 16 + (l & 15);
        bfv[j] = *reinterpret_cast<const bf16x8*>(
            reinterpret_cast<const char*>(Bs) + row * 128 + (kb ^ ((row & 7) << 4)));
      }
#pragma unroll
      for (int i = 0; i < 4; ++i)
#pragma unroll
        for (int j = 0; j < 4; ++j)
          acc[i][j] = __builtin_amdgcn_mfma_f32_16x16x32_bf16(af[i], bfv[j], acc[i][j], 0, 0, 0);
    }
    __syncthreads();
  }

  const int crow0 = m0 + wm + ((l >> 4) << 2);
  const int ccol0 = n0 + wn + (l & 15);
#pragma unroll
  for (int j = 0; j < 4; ++j) {
    const float bv = Bias[ccol0 + j * 16];
#pragma unroll
    for (int i = 0; i < 4; ++i)
#pragma unroll
      for (int rg = 0; rg < 4; ++rg)
        Out[(size_t)(crow0 + i * 16 + rg) * OUT_F + ccol0 + j * 16] = acc[i][j][rg] + bv;
  }
}

extern "C" void kernel_launch(void* const* d_in, const int* in_sizes, int n_in,
                              void* d_out, int out_size, void* d_ws, size_t ws_size,
                              hipStream_t stream) {
  const float* X = (const float*)d_in[0];
  const int* Wp = (const int*)d_in[1];
  const float* Amax = (const float*)d_in[2];
  const float* Bias = (const float*)d_in[3];
  float* Out = (float*)d_out;

  const int M = in_sizes[0] / IN_F;                       // 8192
  const size_t needX = (size_t)M * IN_F * 2;
  const size_t needW = (size_t)OUT_F * IN_F * 2;
  const int grid256 = (M / 256) * (OUT_F / 256);          // 32*43 = 1376

  if (ws_size >= needX + needW && (M % 4096) == 0) {      // Mb%16==0 for supertile map
    unsigned short* Xb = (unsigned short*)d_ws;
    unsigned short* Wb = Xb + (size_t)M * IN_F;
    (void)hipFuncSetAttribute(reinterpret_cast<const void*>(gemm256w16),
                              hipFuncAttributeMaxDynamicSharedMemorySize, 98304);
    prepass<<<4096, 256, 0, stream>>>(X, Xb, M * (IN_F / 8),
                                      Wp, Amax, Wb, OUT_F * (IN_F / 8), 2048);
    gemm256w16<<<grid256, 1024, 98304, stream>>>(Xb, Wb, Bias, Out, M);
  } else {
    const int grid = (M / 128) * (OUT_F / 128);
    nf4_gemm_fused<<<grid, 256, 0, stream>>>(X, Wp, Amax, Bias, Out, M);
  }
}